// Round 1
// baseline (225.629 us; speedup 1.0000x reference)
//
#include <hip/hip_runtime.h>

#define DIM 4096
#define HAD_SCALE 0.015625f  // 1/sqrt(4096) = 1/64

// XOR swizzle: injects bits 6-8 into bank bits 2-4. Bijective on [0,4096),
// preserves 16B (float4) contiguity/alignment since bits 0-1 untouched and
// the mask depends only on bits >= 6.
__device__ __forceinline__ int swz(int a) {
    return a ^ (((a >> 6) & 7) << 2);
}

// Full 4-bit Walsh-Hadamard transform over 16 registers. Butterflies on
// distinct bits commute, so index<->bit assignment is arbitrary as long as
// all 4 bits are covered.
__device__ __forceinline__ void fwht16(float r[16]) {
#pragma unroll
    for (int s = 1; s < 16; s <<= 1) {
#pragma unroll
        for (int i = 0; i < 16; i++) {
            if ((i & s) == 0) {
                float a = r[i];
                float b = r[i ^ s];
                r[i]     = a + b;   // matches ref: new[j]     = old[j] + old[j+blk]
                r[i ^ s] = a - b;   //             new[j+blk] = old[j] - old[j+blk]
            }
        }
    }
}

// One block per 4096-float row. 256 threads x 16 floats.
// Phase 1: bits {0,1,10,11} (float4-load layout, no exchange needed)
// Phase 2: bits {2,3,4,5}   (after LDS transpose 1)
// Phase 3: bits {6,7,8,9}   (after LDS transpose 2), then scaled store.
__global__ __launch_bounds__(256) void fwht_kernel(const float* __restrict__ x,
                                                   float* __restrict__ y) {
    __shared__ float lds[DIM];  // 16 KiB
    const int t = threadIdx.x;
    const size_t row = blockIdx.x;
    const float* xin = x + row * DIM;
    float* yout = y + row * DIM;

    float r[16];

    // ---- Load: thread t gets elements j = 1024*c + 4*t + e  (c,e in [0,4))
    // Coalesced: each wave instruction reads a contiguous 1 KiB segment.
    const float4* __restrict__ x4 = (const float4*)xin;
#pragma unroll
    for (int c = 0; c < 4; c++) {
        float4 v = x4[c * 256 + t];
        r[4 * c + 0] = v.x;
        r[4 * c + 1] = v.y;
        r[4 * c + 2] = v.z;
        r[4 * c + 3] = v.w;
    }
    fwht16(r);  // transforms bits {0,1} (e) and {10,11} (c)

    // ---- Transpose 1: write phase-1 layout (b128, conflict-free under swz)
#pragma unroll
    for (int c = 0; c < 4; c++) {
        int a = swz(4 * t + 1024 * c);
        *(float4*)&lds[a] = make_float4(r[4 * c + 0], r[4 * c + 1],
                                        r[4 * c + 2], r[4 * c + 3]);
    }
    __syncthreads();

    // ---- Phase 2: thread owns j = (t&3) + 4*m + 64*(t>>2), m = bits 2-5.
    // swz makes these stride-4 reads 2-way (free) instead of 16-way.
    const int baseB = (t & 3) + ((t >> 2) << 6);
#pragma unroll
    for (int m = 0; m < 16; m++) r[m] = lds[swz(baseB + (m << 2))];
    fwht16(r);  // transforms bits {2,3,4,5}
    // Write back to the SAME addresses this thread read -> no sync needed
    // between the read above and this write.
#pragma unroll
    for (int m = 0; m < 16; m++) lds[swz(baseB + (m << 2))] = r[m];
    __syncthreads();

    // ---- Phase 3: thread owns j = (t&63) + 64*m + 1024*(t>>6), m = bits 6-9.
    const int baseC = (t & 63) + ((t >> 6) << 10);
#pragma unroll
    for (int m = 0; m < 16; m++) r[m] = lds[swz(baseC + (m << 6))];
    fwht16(r);  // transforms bits {6,7,8,9}

    // ---- Store: for fixed m each wave instruction writes a contiguous
    // 256 B segment; the 16 stores per wave cover a contiguous 4 KiB region.
#pragma unroll
    for (int m = 0; m < 16; m++) yout[baseC + (m << 6)] = r[m] * HAD_SCALE;
}

extern "C" void kernel_launch(void* const* d_in, const int* in_sizes, int n_in,
                              void* d_out, int out_size, void* d_ws, size_t ws_size,
                              hipStream_t stream) {
    const float* x = (const float*)d_in[0];
    float* y = (float*)d_out;
    const int n = in_sizes[0];
    const int rows = n / DIM;  // 8192 for (4, 2048, 4096)
    fwht_kernel<<<rows, 256, 0, stream>>>(x, y);
}